// Round 1
// baseline (294.536 us; speedup 1.0000x reference)
//
#include <hip/hip_runtime.h>
#include <hip/hip_bf16.h>

// Sampler: greedy argmax over vocab of last-token logits.
// logits: [B=64, S=8, V=128000] f32 -> out: [B,1] int32
//
// Memory-bound: 64 * 128000 * 4 B = 32.77 MB read. Two-phase reduction,
// packed (orderable-f32 << 32) | ~index keys so max-reduce == first-argmax.

#define BATCH 64
#define SEQ 8
#define VOCAB 128000
#define V4 (VOCAB / 4)   // 32000 float4 per row
#define SPLIT 16         // segments per row -> 64*16 = 1024 blocks
#define TPB 256

__device__ __forceinline__ unsigned int orderable(float f) {
    unsigned int u = __float_as_uint(f);
    // monotonic map: negative floats reverse, positive floats offset above
    return (u & 0x80000000u) ? ~u : (u | 0x80000000u);
}

__global__ __launch_bounds__(TPB) void argmax_phase1(
        const float* __restrict__ logits,
        unsigned long long* __restrict__ ws) {
    const int row = blockIdx.x / SPLIT;
    const int seg = blockIdx.x % SPLIT;

    // last-token slice of this batch row
    const float4* p = (const float4*)(logits + ((size_t)row * SEQ + (SEQ - 1)) * VOCAB);

    float best = -__builtin_inff();
    int bidx = 0;
    // strided over the whole row by (SPLIT*TPB) float4s; all threads get work
    for (int i = seg * TPB + threadIdx.x; i < V4; i += SPLIT * TPB) {
        float4 v = p[i];
        int base = i * 4;
        // strictly > keeps the lowest index within this thread's increasing scan
        if (v.x > best) { best = v.x; bidx = base;     }
        if (v.y > best) { best = v.y; bidx = base + 1; }
        if (v.z > best) { best = v.z; bidx = base + 2; }
        if (v.w > best) { best = v.w; bidx = base + 3; }
    }

    // pack: high 32 = orderable value (bigger = better),
    //       low 32  = ~index (bigger = smaller index -> first occurrence wins ties)
    unsigned long long key =
        ((unsigned long long)orderable(best) << 32) | (unsigned int)(~bidx);

    __shared__ unsigned long long s[TPB];
    s[threadIdx.x] = key;
    __syncthreads();
    for (int off = TPB / 2; off > 0; off >>= 1) {
        if (threadIdx.x < off) {
            unsigned long long o = s[threadIdx.x + off];
            if (o > s[threadIdx.x]) s[threadIdx.x] = o;
        }
        __syncthreads();
    }
    if (threadIdx.x == 0) ws[blockIdx.x] = s[0];
}

__global__ __launch_bounds__(64) void argmax_phase2(
        const unsigned long long* __restrict__ ws,
        int* __restrict__ out) {
    const int t = threadIdx.x;  // one thread per batch row
    unsigned long long best = 0;
    for (int i = 0; i < SPLIT; ++i) {
        unsigned long long k = ws[t * SPLIT + i];
        if (k > best) best = k;
    }
    out[t] = (int)(~(unsigned int)best);
}

extern "C" void kernel_launch(void* const* d_in, const int* in_sizes, int n_in,
                              void* d_out, int out_size, void* d_ws, size_t ws_size,
                              hipStream_t stream) {
    const float* logits = (const float*)d_in[0];
    int* out = (int*)d_out;
    unsigned long long* ws = (unsigned long long*)d_ws;  // 1024 * 8 B = 8 KB

    argmax_phase1<<<BATCH * SPLIT, TPB, 0, stream>>>(logits, ws);
    argmax_phase2<<<1, 64, 0, stream>>>(ws, out);
}

// Round 2
// 293.613 us; speedup vs baseline: 1.0031x; 1.0031x over previous
//
#include <hip/hip_runtime.h>
#include <hip/hip_bf16.h>

// Sampler: greedy argmax over vocab of last-token logits.
// logits: [B=64, S=8, V=128000] f32 -> out: [B,1] int32
//
// Memory-bound: mandatory read = 64 * 128000 * 4 B = 32.77 MB (~5 us at 6.6 TB/s).
// Two-phase reduction with packed (orderable-f32 << 32) | ~index keys so a
// 64-bit max-reduce == first-occurrence argmax (matches jnp.argmax ties).

#define BATCH 64
#define SEQ 8
#define VOCAB 128000
#define V4 (VOCAB / 4)   // 32000 float4 per row
#define SPLIT 32         // segments per row -> 64*32 = 2048 blocks (8/CU)
#define TPB 256

__device__ __forceinline__ unsigned int orderable(float f) {
    unsigned int u = __float_as_uint(f);
    // monotonic map: negative floats reverse, positive floats offset above
    return (u & 0x80000000u) ? ~u : (u | 0x80000000u);
}

__global__ __launch_bounds__(TPB) void argmax_phase1(
        const float* __restrict__ logits,
        unsigned long long* __restrict__ ws) {
    const int row = blockIdx.x / SPLIT;
    const int seg = blockIdx.x % SPLIT;

    // last-token slice of this batch row
    const float4* p = (const float4*)(logits + ((size_t)row * SEQ + (SEQ - 1)) * VOCAB);

    float best = -__builtin_inff();
    int bidx = 0;
    for (int i = seg * TPB + threadIdx.x; i < V4; i += SPLIT * TPB) {
        float4 v = p[i];
        int base = i * 4;
        // strictly > keeps the lowest index within this thread's increasing scan
        if (v.x > best) { best = v.x; bidx = base;     }
        if (v.y > best) { best = v.y; bidx = base + 1; }
        if (v.z > best) { best = v.z; bidx = base + 2; }
        if (v.w > best) { best = v.w; bidx = base + 3; }
    }

    // pack: high 32 = orderable value (bigger = better),
    //       low 32  = ~index (bigger = smaller index -> first occurrence wins ties)
    unsigned long long key =
        ((unsigned long long)orderable(best) << 32) | (unsigned int)(~bidx);

    // wave-64 shuffle reduction (no LDS tree, 1 barrier total)
    #pragma unroll
    for (int off = 32; off > 0; off >>= 1) {
        unsigned long long o = __shfl_down(key, off, 64);
        if (o > key) key = o;
    }

    __shared__ unsigned long long s[TPB / 64];
    const int lane = threadIdx.x & 63;
    const int wave = threadIdx.x >> 6;
    if (lane == 0) s[wave] = key;
    __syncthreads();
    if (threadIdx.x == 0) {
        unsigned long long k = s[0];
        #pragma unroll
        for (int w = 1; w < TPB / 64; ++w)
            if (s[w] > k) k = s[w];
        ws[blockIdx.x] = k;
    }
}

__global__ __launch_bounds__(64) void argmax_phase2(
        const unsigned long long* __restrict__ ws,
        int* __restrict__ out) {
    const int t = threadIdx.x;  // one thread per batch row
    unsigned long long best = 0;
    #pragma unroll
    for (int i = 0; i < SPLIT; ++i) {
        unsigned long long k = ws[t * SPLIT + i];
        if (k > best) best = k;
    }
    out[t] = (int)(~(unsigned int)best);
}

extern "C" void kernel_launch(void* const* d_in, const int* in_sizes, int n_in,
                              void* d_out, int out_size, void* d_ws, size_t ws_size,
                              hipStream_t stream) {
    const float* logits = (const float*)d_in[0];
    int* out = (int*)d_out;
    unsigned long long* ws = (unsigned long long*)d_ws;  // 2048 * 8 B = 16 KB

    argmax_phase1<<<BATCH * SPLIT, TPB, 0, stream>>>(logits, ws);
    argmax_phase2<<<1, 64, 0, stream>>>(ws, out);
}